// Round 10
// baseline (2280.742 us; speedup 1.0000x reference)
//
#include <hip/hip_runtime.h>
#include <hip/hip_bf16.h>

#define NN 100000
#define NE 1600000
#define D  128
#define BNODES 196                              // nodes per bucket (LDS-sized)
#define NBUK ((NN + BNODES - 1) / BNODES)       // 511
#define BCHUNK 8192                             // edges per binning block

typedef short bf16x8 __attribute__((ext_vector_type(8)));
typedef float f32x4 __attribute__((ext_vector_type(4)));

static __device__ inline unsigned short f2b(float f) {
    __hip_bfloat16 b = __float2bfloat16(f);   // RNE
    unsigned short u;
    __builtin_memcpy(&u, &b, 2);
    return u;
}

// coarse bucket histogram: 511 buckets, LDS-aggregated
__global__ __launch_bounds__(256) void bucket_count(const int* __restrict__ ei,
                                                    int* __restrict__ bcnt) {
    __shared__ int hist[NBUK];
    int chunk0 = blockIdx.x * BCHUNK;
    for (int t = threadIdx.x; t < NBUK; t += 256) hist[t] = 0;
    __syncthreads();
    for (int i = 0; i < BCHUNK; i += 256) {
        int e = chunk0 + i + threadIdx.x;
        if (e < NE) atomicAdd(&hist[(unsigned)ei[NE + e] / BNODES], 1);
    }
    __syncthreads();
    for (int t = threadIdx.x; t < NBUK; t += 256)
        if (hist[t]) atomicAdd(&bcnt[t], hist[t]);
}

// single-block exclusive scan of the 511 bucket counts -> bbase (+end) and gcur
__global__ __launch_bounds__(512) void scan512(const int* __restrict__ bcnt,
                                               int* __restrict__ bbase,
                                               int* __restrict__ gcur) {
    __shared__ int s[512];
    int t = threadIdx.x;
    int v = (t < NBUK) ? bcnt[t] : 0;
    s[t] = v;
    __syncthreads();
    for (int off = 1; off < 512; off <<= 1) {
        int tv = (t >= off) ? s[t - off] : 0;
        __syncthreads();
        s[t] += tv;
        __syncthreads();
    }
    if (t < NBUK) {
        int excl = s[t] - v;
        bbase[t] = excl;
        gcur[t] = excl;
    }
    if (t == 0) bbase[NBUK] = NE;
}

// bin edges by dst bucket into packed 4B entries: (dstLocal<<17) | src
__global__ __launch_bounds__(256) void bin_scatter(const int* __restrict__ ei,
                                                   int* __restrict__ gcur,
                                                   unsigned* __restrict__ ebuf) {
    __shared__ int hist[NBUK];
    __shared__ int base_s[NBUK];
    int chunk0 = blockIdx.x * BCHUNK;
    for (int t = threadIdx.x; t < NBUK; t += 256) hist[t] = 0;
    __syncthreads();
    for (int i = 0; i < BCHUNK; i += 256) {
        int e = chunk0 + i + threadIdx.x;
        if (e < NE) atomicAdd(&hist[(unsigned)ei[NE + e] / BNODES], 1);
    }
    __syncthreads();
    for (int t = threadIdx.x; t < NBUK; t += 256) {
        base_s[t] = hist[t] ? atomicAdd(&gcur[t], hist[t]) : 0;
        hist[t] = 0;
    }
    __syncthreads();
    for (int i = 0; i < BCHUNK; i += 256) {
        int e = chunk0 + i + threadIdx.x;
        if (e < NE) {
            int s = ei[e];
            int d = ei[NE + e];
            int b = (unsigned)d / BNODES;
            int dl = d - b * BNODES;
            int off = atomicAdd(&hist[b], 1);
            ebuf[(size_t)base_s[b] + off] = ((unsigned)dl << 17) | (unsigned)s;
        }
    }
}

// fp32 -> bf16 conversion, 4 elems/thread
__global__ void conv_f2b(const float* __restrict__ src,
                         unsigned short* __restrict__ dst, int n) {
    int i = (blockIdx.x * 256 + threadIdx.x) * 4;
    if (i + 3 < n) {
        float4 v = *(const float4*)(src + i);
        ushort4 o;
        o.x = f2b(v.x); o.y = f2b(v.y); o.z = f2b(v.z); o.w = f2b(v.w);
        *(ushort4*)(dst + i) = o;
    } else {
        for (; i < n; ++i) dst[i] = f2b(src[i]);
    }
}

// all 4 weight matrices (each D*D) in one launch; dsts contiguous
__global__ void conv_w4(const float* __restrict__ s0, const float* __restrict__ s1,
                        const float* __restrict__ s2, const float* __restrict__ s3,
                        unsigned short* __restrict__ dst) {
    int i = (blockIdx.x * 256 + threadIdx.x) * 4;   // [0, 4*D*D)
    const float* srcs[4] = {s0, s1, s2, s3};
    const float* s = srcs[i >> 14];                 // D*D = 16384
    float4 v = *(const float4*)(s + (i & 16383));
    ushort4 o;
    o.x = f2b(v.x); o.y = f2b(v.y); o.z = f2b(v.z); o.w = f2b(v.w);
    *(ushort4*)(dst + i) = o;
}

// Bucket-LDS mean aggregation: one block per 196-node bucket.
// Streams the bucket's packed edge segment; each 32-lane half-wave handles one
// edge (uint2/lane = full 256B row), 8 edges in flight. fp32 accumulate via
// ds_add_f32 into channel-swizzled LDS (ch=4*sl+k -> acc[n][k*32+sl]) so all
// 32 lanes hit distinct banks. Degree counted in-block (bucket holds each
// node's complete edge list). No CSR needed.
__global__ __launch_bounds__(512) void aggregate_bucket(
    const unsigned short* __restrict__ hb,
    const unsigned* __restrict__ ebuf,
    const int* __restrict__ bbase,
    unsigned short* __restrict__ aggb)
{
    __shared__ float acc[BNODES][D];   // 100352 B
    __shared__ int deg[BNODES];
    const int b = blockIdx.x;
    const int node0 = b * BNODES;
    const int tid = threadIdx.x;

    float4* az = (float4*)&acc[0][0];
    for (int i = tid; i < BNODES * D / 4; i += 512) az[i] = (float4){0.f, 0.f, 0.f, 0.f};
    for (int i = tid; i < BNODES; i += 512) deg[i] = 0;
    __syncthreads();

    const int beg = bbase[b], end = bbase[b + 1];
    const int hw = tid >> 5;     // half-wave 0..15
    const int sl = tid & 31;
    const uint2* hp = (const uint2*)hb;   // 32 uint2 per row

    int j = beg + hw;
#define EDGE_BODY(P, V)                                                        \
    {                                                                          \
        int dl_ = (int)((P) >> 17);                                            \
        if (sl == 0) atomicAdd(&deg[dl_], 1);                                  \
        atomicAdd(&acc[dl_][sl],      __uint_as_float((V).x << 16));           \
        atomicAdd(&acc[dl_][32 + sl], __uint_as_float((V).x & 0xffff0000u));   \
        atomicAdd(&acc[dl_][64 + sl], __uint_as_float((V).y << 16));           \
        atomicAdd(&acc[dl_][96 + sl], __uint_as_float((V).y & 0xffff0000u));   \
    }
    for (; j + 112 < end; j += 128) {
        unsigned p[8];
        uint2 v[8];
#pragma unroll
        for (int q = 0; q < 8; ++q) p[q] = ebuf[j + q * 16];
#pragma unroll
        for (int q = 0; q < 8; ++q) v[q] = hp[(size_t)(p[q] & 0x1ffffu) * 32 + sl];
#pragma unroll
        for (int q = 0; q < 8; ++q) EDGE_BODY(p[q], v[q]);
    }
    for (; j < end; j += 16) {
        unsigned p = ebuf[j];
        uint2 v = hp[(size_t)(p & 0x1ffffu) * 32 + sl];
        EDGE_BODY(p, v);
    }
#undef EDGE_BODY
    __syncthreads();

    const int nn = min(BNODES, NN - node0);
    for (int n = hw; n < nn; n += 16) {
        float inv = 1.0f / (float)(deg[n] > 1 ? deg[n] : 1);
        float a0 = acc[n][sl] * inv;
        float a1 = acc[n][32 + sl] * inv;
        float a2 = acc[n][64 + sl] * inv;
        float a3 = acc[n][96 + sl] * inv;
        uint2 o;
        o.x = (unsigned)f2b(a0) | ((unsigned)f2b(a1) << 16);
        o.y = (unsigned)f2b(a2) | ((unsigned)f2b(a3) << 16);
        ((uint2*)aggb)[(size_t)(node0 + n) * 32 + sl] = o;
    }
}

// out[n][j] = leaky_relu( sum_k agg[n][k]*Wl[j][k] + h[n][k]*Wr[j][k] + b[j], 0.5 )
// MFMA 16x16x32 bf16. Block = 256 thr = 4 waves (2x2), block tile 64 rows x 128 cols,
// wave tile 32 rows x 64 cols. No LDS, no barriers: fragments load direct from global.
template <int OUT_F32>
__global__ __launch_bounds__(256) void sage_gemm_mfma(
    const unsigned short* __restrict__ Ab,   // [NN][128] aggregated
    const unsigned short* __restrict__ Hb,   // [NN][128] root
    const unsigned short* __restrict__ Wlb,  // [128][128], row j contiguous in k
    const unsigned short* __restrict__ Wrb,
    const float* __restrict__ bias,
    float* __restrict__ outf,
    unsigned short* __restrict__ outb)
{
    const int lane = threadIdx.x & 63;
    const int wid  = threadIdx.x >> 6;
    const int r  = lane & 15;
    const int kg = lane >> 4;
    const int row0 = blockIdx.x * 64 + (wid >> 1) * 32;
    const int col0 = (wid & 1) * 64;

    const int ra0 = min(row0 + r,      NN - 1);
    const int ra1 = min(row0 + 16 + r, NN - 1);

    float bv[4];
#pragma unroll
    for (int c = 0; c < 4; ++c) bv[c] = bias[col0 + c * 16 + r];

    f32x4 acc[2][4];
#pragma unroll
    for (int m = 0; m < 2; ++m)
#pragma unroll
        for (int c = 0; c < 4; ++c) acc[m][c] = (f32x4){0.f, 0.f, 0.f, 0.f};

#pragma unroll
    for (int ks = 0; ks < 8; ++ks) {
        const unsigned short* S = (ks < 4) ? Ab : Hb;
        const unsigned short* W = (ks < 4) ? Wlb : Wrb;
        const int kk = (ks & 3) * 32 + kg * 8;
        bf16x8 a0 = *(const bf16x8*)(S + (size_t)ra0 * D + kk);
        bf16x8 a1 = *(const bf16x8*)(S + (size_t)ra1 * D + kk);
        bf16x8 bw[4];
#pragma unroll
        for (int c = 0; c < 4; ++c)
            bw[c] = *(const bf16x8*)(W + (size_t)(col0 + c * 16 + r) * D + kk);
#pragma unroll
        for (int c = 0; c < 4; ++c) {
            acc[0][c] = __builtin_amdgcn_mfma_f32_16x16x32_bf16(a0, bw[c], acc[0][c], 0, 0, 0);
            acc[1][c] = __builtin_amdgcn_mfma_f32_16x16x32_bf16(a1, bw[c], acc[1][c], 0, 0, 0);
        }
    }

    // C/D layout: col = c*16 + (lane&15), row = m*16 + (lane>>4)*4 + q   [m89]
#pragma unroll
    for (int m = 0; m < 2; ++m) {
#pragma unroll
        for (int q = 0; q < 4; ++q) {
            int row = row0 + m * 16 + kg * 4 + q;
            if (row < NN) {
#pragma unroll
                for (int c = 0; c < 4; ++c) {
                    float v = acc[m][c][q] + bv[c];
                    v = v > 0.f ? v : 0.5f * v;
                    int colj = col0 + c * 16 + r;
                    if (OUT_F32) outf[(size_t)row * D + colj] = v;
                    else         outb[(size_t)row * D + colj] = f2b(v);
                }
            }
        }
    }
}

extern "C" void kernel_launch(void* const* d_in, const int* in_sizes, int n_in,
                              void* d_out, int out_size, void* d_ws, size_t ws_size,
                              hipStream_t stream) {
    const float* x   = (const float*)d_in[0];
    const int*   ei  = (const int*)d_in[1];
    const float* W1l = (const float*)d_in[2];
    const float* W1r = (const float*)d_in[3];
    const float* b1  = (const float*)d_in[4];
    const float* W2l = (const float*)d_in[5];
    const float* W2r = (const float*)d_in[6];
    const float* b2  = (const float*)d_in[7];
    float* out = (float*)d_out;

    char* ws = (char*)d_ws;
    size_t off = 0;
    auto alloc = [&](size_t bytes) {
        void* p = ws + off;
        off = (off + bytes + 255) & ~(size_t)255;
        return p;
    };
    int* bcnt  = (int*)alloc((NBUK + 1) * 4);
    int* bbase = (int*)alloc((NBUK + 1) * 4);
    int* gcur  = (int*)alloc((NBUK + 1) * 4);
    unsigned* ebuf = (unsigned*)alloc((size_t)NE * 4);   // live through both layers
    unsigned short* xb   = (unsigned short*)alloc((size_t)NN * D * 2);
    unsigned short* aggb = (unsigned short*)alloc((size_t)NN * D * 2);
    unsigned short* h1b  = (unsigned short*)alloc((size_t)NN * D * 2);
    unsigned short* wb   = (unsigned short*)alloc((size_t)4 * D * D * 2);
    unsigned short* w1lb = wb;
    unsigned short* w1rb = wb + D * D;
    unsigned short* w2lb = wb + 2 * D * D;
    unsigned short* w2rb = wb + 3 * D * D;

    // ---- edge binning (bucket-grouped packed edges; no CSR) ----
    hipMemsetAsync(bcnt, 0, (NBUK + 1) * 4, stream);
    bucket_count<<<(NE + BCHUNK - 1) / BCHUNK, 256, 0, stream>>>(ei, bcnt);
    scan512<<<1, 512, 0, stream>>>(bcnt, bbase, gcur);
    bin_scatter<<<(NE + BCHUNK - 1) / BCHUNK, 256, 0, stream>>>(ei, gcur, ebuf);

    // ---- bf16 conversions ----
    conv_f2b<<<(NN * D / 4 + 255) / 256, 256, 0, stream>>>(x, xb, NN * D);
    conv_w4<<<(4 * D * D / 4 + 255) / 256, 256, 0, stream>>>(W1l, W1r, W2l, W2r, wb);

    // ---- layer 1 ----
    aggregate_bucket<<<NBUK, 512, 0, stream>>>(xb, ebuf, bbase, aggb);
    sage_gemm_mfma<0><<<(NN + 63) / 64, 256, 0, stream>>>(aggb, xb, w1lb, w1rb, b1,
                                                          nullptr, h1b);
    // ---- layer 2 ----
    aggregate_bucket<<<NBUK, 512, 0, stream>>>(h1b, ebuf, bbase, aggb);
    sage_gemm_mfma<1><<<(NN + 63) / 64, 256, 0, stream>>>(aggb, h1b, w2lb, w2rb, b2,
                                                          out, nullptr);
}

// Round 11
// 398.982 us; speedup vs baseline: 5.7164x; 5.7164x over previous
//
#include <hip/hip_runtime.h>
#include <hip/hip_bf16.h>

#define NN 100000
#define NE 1600000
#define D  128
#define SCAN_CHUNK 1024
#define NSCAN ((NN + SCAN_CHUNK - 1) / SCAN_CHUNK)   // 98
#define NB 98          // dst buckets of 1024 nodes (dst>>10)
#define BCHUNK 8192    // edges per binning block

typedef short bf16x8 __attribute__((ext_vector_type(8)));
typedef float f32x4 __attribute__((ext_vector_type(4)));

static __device__ inline unsigned short f2b(float f) {
    __hip_bfloat16 b = __float2bfloat16(f);   // RNE
    unsigned short u;
    __builtin_memcpy(&u, &b, 2);
    return u;
}

// coarse bucket histogram: 98 buckets, LDS-aggregated
__global__ __launch_bounds__(256) void bucket_count(const int* __restrict__ ei,
                                                    int* __restrict__ bcnt) {
    __shared__ int hist[NB];
    int chunk0 = blockIdx.x * BCHUNK;
    for (int t = threadIdx.x; t < NB; t += 256) hist[t] = 0;
    __syncthreads();
    for (int i = 0; i < BCHUNK; i += 256) {
        int e = chunk0 + i + threadIdx.x;
        if (e < NE) atomicAdd(&hist[ei[NE + e] >> 10], 1);
    }
    __syncthreads();
    for (int t = threadIdx.x; t < NB; t += 256)
        if (hist[t]) atomicAdd(&bcnt[t], hist[t]);
}

// exclusive scan of 98 bucket counts -> bbase (with end sentinel) and gcur
__global__ void scan98(const int* __restrict__ bcnt, int* __restrict__ bbase,
                       int* __restrict__ gcur) {
    __shared__ int s[128];
    int t = threadIdx.x;
    int v = (t < NB) ? bcnt[t] : 0;
    s[t] = v;
    __syncthreads();
    for (int off = 1; off < 128; off <<= 1) {
        int tv = (t >= off) ? s[t - off] : 0;
        __syncthreads();
        s[t] += tv;
        __syncthreads();
    }
    if (t < NB) { bbase[t] = s[t] - v; gcur[t] = s[t] - v; }
    if (t == 0) bbase[NB] = NE;
}

// bin edges by dst>>10 into packed 4B entries: (dstLocal10<<17) | src17
__global__ __launch_bounds__(256) void bin_scatter(const int* __restrict__ ei,
                                                   int* __restrict__ gcur,
                                                   unsigned* __restrict__ ebuf) {
    __shared__ int hist[NB];
    __shared__ int base_s[NB];
    int chunk0 = blockIdx.x * BCHUNK;
    for (int t = threadIdx.x; t < NB; t += 256) hist[t] = 0;
    __syncthreads();
    for (int i = 0; i < BCHUNK; i += 256) {
        int e = chunk0 + i + threadIdx.x;
        if (e < NE) atomicAdd(&hist[ei[NE + e] >> 10], 1);
    }
    __syncthreads();
    for (int t = threadIdx.x; t < NB; t += 256) {
        base_s[t] = hist[t] ? atomicAdd(&gcur[t], hist[t]) : 0;
        hist[t] = 0;
    }
    __syncthreads();
    for (int i = 0; i < BCHUNK; i += 256) {
        int e = chunk0 + i + threadIdx.x;
        if (e < NE) {
            int s = ei[e];
            int d = ei[NE + e];
            int b = d >> 10;
            int off = atomicAdd(&hist[b], 1);
            ebuf[(size_t)base_s[b] + off] = ((unsigned)(d & 1023) << 17) | (unsigned)s;
        }
    }
}

// per-node counts from bucket-grouped packed edges; grid = NB*8 sub-blocks,
// atomics land in the bucket's 4KB cnt window (cache-localized)
__global__ __launch_bounds__(256) void hist2(const unsigned* __restrict__ ebuf,
                                             const int* __restrict__ bbase,
                                             int* __restrict__ cnt) {
    int b = blockIdx.x >> 3, q = blockIdx.x & 7;
    int node0 = b << 10;
    int beg = bbase[b], end = bbase[b + 1];
    for (int j = beg + q * 256 + threadIdx.x; j < end; j += 2048)
        atomicAdd(&cnt[node0 + (int)(ebuf[j] >> 17)], 1);
}

// per-1024-chunk exclusive scan, emit chunk sums
__global__ void scanA(const int* __restrict__ cnt, int* __restrict__ rowptr,
                      int* __restrict__ bsum) {
    __shared__ int lds[256];
    int tid  = threadIdx.x;
    int base = blockIdx.x * SCAN_CHUNK + tid * 4;
    int v[4];
#pragma unroll
    for (int i = 0; i < 4; ++i) v[i] = (base + i < NN) ? cnt[base + i] : 0;
    int s = v[0] + v[1] + v[2] + v[3];
    lds[tid] = s;
    __syncthreads();
    for (int off = 1; off < 256; off <<= 1) {
        int t = (tid >= off) ? lds[tid - off] : 0;
        __syncthreads();
        lds[tid] += t;
        __syncthreads();
    }
    int excl = lds[tid] - s;
    if (tid == 255) bsum[blockIdx.x] = lds[255];
    int run = excl;
#pragma unroll
    for (int i = 0; i < 4; ++i) {
        if (base + i < NN) rowptr[base + i] = run;
        run += v[i];
    }
}

// exclusive scan of the 98 chunk sums in place
__global__ void scanB(int* __restrict__ a, int nb) {
    __shared__ int s[128];
    int t = threadIdx.x;
    int v = (t < nb) ? a[t] : 0;
    s[t] = v;
    __syncthreads();
    for (int off = 1; off < 128; off <<= 1) {
        int tv = (t >= off) ? s[t - off] : 0;
        __syncthreads();
        s[t] += tv;
        __syncthreads();
    }
    if (t < nb) a[t] = s[t] - v;
}

// finalize rowptr; produce fill cursor (copy)
__global__ void scanC(int* __restrict__ rowptr, const int* __restrict__ bsum,
                      int* __restrict__ cursor) {
    int i = blockIdx.x * 256 + threadIdx.x;
    if (i < NN) {
        int v = rowptr[i] + bsum[i / SCAN_CHUNK];
        rowptr[i] = v;
        cursor[i] = v;
    }
    if (i == 0) rowptr[NN] = NE;
}

// scatter src into node-sorted CSR col; grid = NB*8, L2-resident col window
__global__ __launch_bounds__(256) void fill_from_buckets(
    const unsigned* __restrict__ ebuf, const int* __restrict__ bbase,
    int* __restrict__ cursor, int* __restrict__ col)
{
    int b = blockIdx.x >> 3, q = blockIdx.x & 7;
    int node0 = b << 10;
    int beg = bbase[b], end = bbase[b + 1];
    for (int j = beg + q * 256 + threadIdx.x; j < end; j += 2048) {
        unsigned p = ebuf[j];
        int pos = atomicAdd(&cursor[node0 + (int)(p >> 17)], 1);
        col[pos] = (int)(p & 0x1ffffu);
    }
}

// fp32 -> bf16 conversion, 4 elems/thread
__global__ void conv_f2b(const float* __restrict__ src,
                         unsigned short* __restrict__ dst, int n) {
    int i = (blockIdx.x * 256 + threadIdx.x) * 4;
    if (i + 3 < n) {
        float4 v = *(const float4*)(src + i);
        ushort4 o;
        o.x = f2b(v.x); o.y = f2b(v.y); o.z = f2b(v.z); o.w = f2b(v.w);
        *(ushort4*)(dst + i) = o;
    } else {
        for (; i < n; ++i) dst[i] = f2b(src[i]);
    }
}

// all 4 weight matrices (each D*D) in one launch; dsts contiguous
__global__ void conv_w4(const float* __restrict__ s0, const float* __restrict__ s1,
                        const float* __restrict__ s2, const float* __restrict__ s3,
                        unsigned short* __restrict__ dst) {
    int i = (blockIdx.x * 256 + threadIdx.x) * 4;   // [0, 4*D*D)
    const float* srcs[4] = {s0, s1, s2, s3};
    const float* s = srcs[i >> 14];                 // D*D = 16384
    float4 v = *(const float4*)(s + (i & 16383));
    ushort4 o;
    o.x = f2b(v.x); o.y = f2b(v.y); o.z = f2b(v.z); o.w = f2b(v.w);
    *(ushort4*)(dst + i) = o;
}

// mean aggregation over bf16 features; two 32-lane halves per wave, uint2/lane
// (round-8 proven version: 62 us, 3.3 TB/s)
__global__ __launch_bounds__(256) void aggregate(const unsigned short* __restrict__ hb,
                                                 const int* __restrict__ rowptr,
                                                 const int* __restrict__ col,
                                                 unsigned short* __restrict__ aggb) {
    int node = blockIdx.x * 4 + (threadIdx.x >> 6);
    if (node >= NN) return;
    int lane = threadIdx.x & 63;
    int half = lane >> 5;
    int sl   = lane & 31;
    int beg = rowptr[node], end = rowptr[node + 1];
    const uint2* hp = (const uint2*)hb;   // 32 uint2 per row
    float a0 = 0.f, a1 = 0.f, a2 = 0.f, a3 = 0.f;

    int j = beg + half;
    for (; j + 6 < end; j += 8) {
        int c0 = col[j];
        int c1 = col[j + 2];
        int c2 = col[j + 4];
        int c3 = col[j + 6];
        uint2 v0 = hp[c0 * 32 + sl];
        uint2 v1 = hp[c1 * 32 + sl];
        uint2 v2 = hp[c2 * 32 + sl];
        uint2 v3 = hp[c3 * 32 + sl];
        a0 += __uint_as_float(v0.x << 16) + __uint_as_float(v1.x << 16)
            + __uint_as_float(v2.x << 16) + __uint_as_float(v3.x << 16);
        a1 += __uint_as_float(v0.x & 0xffff0000u) + __uint_as_float(v1.x & 0xffff0000u)
            + __uint_as_float(v2.x & 0xffff0000u) + __uint_as_float(v3.x & 0xffff0000u);
        a2 += __uint_as_float(v0.y << 16) + __uint_as_float(v1.y << 16)
            + __uint_as_float(v2.y << 16) + __uint_as_float(v3.y << 16);
        a3 += __uint_as_float(v0.y & 0xffff0000u) + __uint_as_float(v1.y & 0xffff0000u)
            + __uint_as_float(v2.y & 0xffff0000u) + __uint_as_float(v3.y & 0xffff0000u);
    }
    for (; j < end; j += 2) {
        uint2 v = hp[col[j] * 32 + sl];
        a0 += __uint_as_float(v.x << 16);
        a1 += __uint_as_float(v.x & 0xffff0000u);
        a2 += __uint_as_float(v.y << 16);
        a3 += __uint_as_float(v.y & 0xffff0000u);
    }

    a0 += __shfl_xor(a0, 32);
    a1 += __shfl_xor(a1, 32);
    a2 += __shfl_xor(a2, 32);
    a3 += __shfl_xor(a3, 32);

    int deg = end - beg;
    float inv = 1.0f / (float)(deg > 1 ? deg : 1);
    if (half == 0) {
        uint2 o;
        o.x = (unsigned)f2b(a0 * inv) | ((unsigned)f2b(a1 * inv) << 16);
        o.y = (unsigned)f2b(a2 * inv) | ((unsigned)f2b(a3 * inv) << 16);
        ((uint2*)aggb)[(size_t)node * 32 + sl] = o;
    }
}

// out[n][j] = leaky_relu( sum_k agg[n][k]*Wl[j][k] + h[n][k]*Wr[j][k] + b[j], 0.5 )
// MFMA 16x16x32 bf16. Block = 256 thr = 4 waves (2x2), tile 64 rows x 128 cols.
// A/H slabs staged via coalesced uint4 loads into 272B-padded LDS rows
// (~2-way max bank aliasing on ds_write_b128/ds_read_b128); weights stay
// global (64KB, L2-hot across all blocks).
template <int OUT_F32>
__global__ __launch_bounds__(256) void sage_gemm_mfma(
    const unsigned short* __restrict__ Ab,   // [NN][128] aggregated
    const unsigned short* __restrict__ Hb,   // [NN][128] root
    const unsigned short* __restrict__ Wlb,  // [128][128], row j contiguous in k
    const unsigned short* __restrict__ Wrb,
    const float* __restrict__ bias,
    float* __restrict__ outf,
    unsigned short* __restrict__ outb)
{
    __shared__ unsigned short sA[64][136];   // 17.4 KB (272B rows)
    __shared__ unsigned short sH[64][136];
    const int tid = threadIdx.x;
    const int block0 = blockIdx.x * 64;

    {
        int i = tid;   // 64 rows x 16 quads = 1024; 4 iters of 256 threads
#pragma unroll
        for (int k = 0; k < 4; ++k, i += 256) {
            int row = i >> 4, c16 = i & 15;
            int grow = block0 + row; if (grow >= NN) grow = NN - 1;
            *(uint4*)(&sA[row][c16 * 8]) = *(const uint4*)(Ab + (size_t)grow * D + c16 * 8);
            *(uint4*)(&sH[row][c16 * 8]) = *(const uint4*)(Hb + (size_t)grow * D + c16 * 8);
        }
    }
    __syncthreads();

    const int lane = tid & 63;
    const int wid  = tid >> 6;
    const int r  = lane & 15;
    const int kg = lane >> 4;
    const int rbase = (wid >> 1) * 32;     // 0 or 32
    const int col0  = (wid & 1) * 64;

    float bv[4];
#pragma unroll
    for (int c = 0; c < 4; ++c) bv[c] = bias[col0 + c * 16 + r];

    f32x4 acc[2][4];
#pragma unroll
    for (int m = 0; m < 2; ++m)
#pragma unroll
        for (int c = 0; c < 4; ++c) acc[m][c] = (f32x4){0.f, 0.f, 0.f, 0.f};

#pragma unroll
    for (int ks = 0; ks < 8; ++ks) {
        const unsigned short (*S)[136] = (ks < 4) ? sA : sH;
        const unsigned short* W = (ks < 4) ? Wlb : Wrb;
        const int kk = (ks & 3) * 32 + kg * 8;
        bf16x8 a0 = *(const bf16x8*)(&S[rbase + r][kk]);
        bf16x8 a1 = *(const bf16x8*)(&S[rbase + 16 + r][kk]);
        bf16x8 bw[4];
#pragma unroll
        for (int c = 0; c < 4; ++c)
            bw[c] = *(const bf16x8*)(W + (size_t)(col0 + c * 16 + r) * D + kk);
#pragma unroll
        for (int c = 0; c < 4; ++c) {
            acc[0][c] = __builtin_amdgcn_mfma_f32_16x16x32_bf16(a0, bw[c], acc[0][c], 0, 0, 0);
            acc[1][c] = __builtin_amdgcn_mfma_f32_16x16x32_bf16(a1, bw[c], acc[1][c], 0, 0, 0);
        }
    }

    // C/D layout: col = c*16 + (lane&15), row = m*16 + (lane>>4)*4 + q   [m89]
#pragma unroll
    for (int m = 0; m < 2; ++m) {
#pragma unroll
        for (int q = 0; q < 4; ++q) {
            int row = block0 + rbase + m * 16 + kg * 4 + q;
            if (row < NN) {
#pragma unroll
                for (int c = 0; c < 4; ++c) {
                    float v = acc[m][c][q] + bv[c];
                    v = v > 0.f ? v : 0.5f * v;
                    int colj = col0 + c * 16 + r;
                    if (OUT_F32) outf[(size_t)row * D + colj] = v;
                    else         outb[(size_t)row * D + colj] = f2b(v);
                }
            }
        }
    }
}

extern "C" void kernel_launch(void* const* d_in, const int* in_sizes, int n_in,
                              void* d_out, int out_size, void* d_ws, size_t ws_size,
                              hipStream_t stream) {
    const float* x   = (const float*)d_in[0];
    const int*   ei  = (const int*)d_in[1];
    const float* W1l = (const float*)d_in[2];
    const float* W1r = (const float*)d_in[3];
    const float* b1  = (const float*)d_in[4];
    const float* W2l = (const float*)d_in[5];
    const float* W2r = (const float*)d_in[6];
    const float* b2  = (const float*)d_in[7];
    float* out = (float*)d_out;

    char* ws = (char*)d_ws;
    size_t off = 0;
    auto alloc = [&](size_t bytes) {
        void* p = ws + off;
        off = (off + bytes + 255) & ~(size_t)255;
        return p;
    };
    int* rowptr = (int*)alloc((NN + 1) * 4);
    int* cursor = (int*)alloc((NN + NB + 2) * 4);   // cnt/cursor + bcnt (one memset)
    int* bcnt   = cursor + NN;
    int* bsum   = (int*)alloc(4096);
    int* bbase  = (int*)alloc((NB + 1) * 4);
    int* gcur   = (int*)alloc((NB + 1) * 4);
    int* col    = (int*)alloc((size_t)NE * 4);
    unsigned short* xb   = (unsigned short*)alloc((size_t)NN * D * 2);
    unsigned short* aggb = (unsigned short*)alloc((size_t)NN * D * 2);
    unsigned short* h1b  = (unsigned short*)alloc((size_t)NN * D * 2);
    unsigned short* wb   = (unsigned short*)alloc((size_t)4 * D * D * 2);
    unsigned short* w1lb = wb;
    unsigned short* w1rb = wb + D * D;
    unsigned short* w2lb = wb + 2 * D * D;
    unsigned short* w2rb = wb + 3 * D * D;
    // ebuf (6.4 MB) aliases h1b (25.6 MB): ebuf dead before h1b is written
    unsigned* ebuf = (unsigned*)h1b;

    // ---- CSR build (packed 4B edges; no random per-node atomics) ----
    hipMemsetAsync(cursor, 0, (size_t)(NN + NB + 1) * 4, stream);
    bucket_count<<<(NE + BCHUNK - 1) / BCHUNK, 256, 0, stream>>>(ei, bcnt);
    scan98<<<1, 128, 0, stream>>>(bcnt, bbase, gcur);
    bin_scatter<<<(NE + BCHUNK - 1) / BCHUNK, 256, 0, stream>>>(ei, gcur, ebuf);
    hist2<<<NB * 8, 256, 0, stream>>>(ebuf, bbase, cursor);
    scanA<<<NSCAN, 256, 0, stream>>>(cursor, rowptr, bsum);
    scanB<<<1, 128, 0, stream>>>(bsum, NSCAN);
    scanC<<<(NN + 255) / 256, 256, 0, stream>>>(rowptr, bsum, cursor);
    fill_from_buckets<<<NB * 8, 256, 0, stream>>>(ebuf, bbase, cursor, col);

    // ---- bf16 conversions ----
    conv_f2b<<<(NN * D / 4 + 255) / 256, 256, 0, stream>>>(x, xb, NN * D);
    conv_w4<<<(4 * D * D / 4 + 255) / 256, 256, 0, stream>>>(W1l, W1r, W2l, W2r, wb);

    // ---- layer 1 ----
    aggregate<<<(NN + 3) / 4, 256, 0, stream>>>(xb, rowptr, col, aggb);
    sage_gemm_mfma<0><<<(NN + 63) / 64, 256, 0, stream>>>(aggb, xb, w1lb, w1rb, b1,
                                                          nullptr, h1b);
    // ---- layer 2 ----
    aggregate<<<(NN + 3) / 4, 256, 0, stream>>>(h1b, rowptr, col, aggb);
    sage_gemm_mfma<1><<<(NN + 63) / 64, 256, 0, stream>>>(aggb, h1b, w2lb, w2rb, b2,
                                                          out, nullptr);
}

// Round 12
// 278.725 us; speedup vs baseline: 8.1828x; 1.4315x over previous
//
#include <hip/hip_runtime.h>
#include <hip/hip_bf16.h>

#define NN 100000
#define NE 1600000
#define D  128
#define NB 98          // dst buckets of 1024 nodes (dst>>10)
#define BCHUNK 8192    // edges per binning block

typedef short bf16x8 __attribute__((ext_vector_type(8)));
typedef float f32x4 __attribute__((ext_vector_type(4)));

static __device__ inline unsigned short f2b(float f) {
    __hip_bfloat16 b = __float2bfloat16(f);   // RNE
    unsigned short u;
    __builtin_memcpy(&u, &b, 2);
    return u;
}

// coarse bucket histogram: 98 buckets, LDS-aggregated
__global__ __launch_bounds__(256) void bucket_count(const int* __restrict__ ei,
                                                    int* __restrict__ bcnt) {
    __shared__ int hist[NB];
    int chunk0 = blockIdx.x * BCHUNK;
    for (int t = threadIdx.x; t < NB; t += 256) hist[t] = 0;
    __syncthreads();
    for (int i = 0; i < BCHUNK; i += 256) {
        int e = chunk0 + i + threadIdx.x;
        if (e < NE) atomicAdd(&hist[ei[NE + e] >> 10], 1);
    }
    __syncthreads();
    for (int t = threadIdx.x; t < NB; t += 256)
        if (hist[t]) atomicAdd(&bcnt[t], hist[t]);
}

// exclusive scan of 98 bucket counts -> bbase (with end sentinel) and gcur
__global__ void scan98(const int* __restrict__ bcnt, int* __restrict__ bbase,
                       int* __restrict__ gcur) {
    __shared__ int s[128];
    int t = threadIdx.x;
    int v = (t < NB) ? bcnt[t] : 0;
    s[t] = v;
    __syncthreads();
    for (int off = 1; off < 128; off <<= 1) {
        int tv = (t >= off) ? s[t - off] : 0;
        __syncthreads();
        s[t] += tv;
        __syncthreads();
    }
    if (t < NB) { bbase[t] = s[t] - v; gcur[t] = s[t] - v; }
    if (t == 0) bbase[NB] = NE;
}

// bin edges by dst>>10 into packed 4B entries: (dstLocal10<<17) | src17
__global__ __launch_bounds__(256) void bin_scatter(const int* __restrict__ ei,
                                                   int* __restrict__ gcur,
                                                   unsigned* __restrict__ ebuf) {
    __shared__ int hist[NB];
    __shared__ int base_s[NB];
    int chunk0 = blockIdx.x * BCHUNK;
    for (int t = threadIdx.x; t < NB; t += 256) hist[t] = 0;
    __syncthreads();
    for (int i = 0; i < BCHUNK; i += 256) {
        int e = chunk0 + i + threadIdx.x;
        if (e < NE) atomicAdd(&hist[ei[NE + e] >> 10], 1);
    }
    __syncthreads();
    for (int t = threadIdx.x; t < NB; t += 256) {
        base_s[t] = hist[t] ? atomicAdd(&gcur[t], hist[t]) : 0;
        hist[t] = 0;
    }
    __syncthreads();
    for (int i = 0; i < BCHUNK; i += 256) {
        int e = chunk0 + i + threadIdx.x;
        if (e < NE) {
            int s = ei[e];
            int d = ei[NE + e];
            int b = d >> 10;
            int off = atomicAdd(&hist[b], 1);
            ebuf[(size_t)base_s[b] + off] = ((unsigned)(d & 1023) << 17) | (unsigned)s;
        }
    }
}

// One block per 1024-node bucket: per-node counts (native LDS int atomics),
// 1024-wide LDS scan -> rowptr, then scatter col through LDS cursors.
// The bucket's 65KB col window is written by exactly ONE block on ONE XCD
// -> L2-resident, no cross-XCD line ping-pong (round-11 fill lesson).
__global__ __launch_bounds__(1024) void sort_bucket(
    const unsigned* __restrict__ ebuf, const int* __restrict__ bbase,
    int* __restrict__ rowptr, int* __restrict__ col)
{
    __shared__ int cnt[1024];
    __shared__ int tmp[1024];
    __shared__ int cur[1024];
    const int b = blockIdx.x;
    const int t = threadIdx.x;
    const int beg = bbase[b], end = bbase[b + 1];
    const int node0 = b << 10;

    cnt[t] = 0;
    __syncthreads();
    for (int j = beg + t; j < end; j += 1024)
        atomicAdd(&cnt[ebuf[j] >> 17], 1);
    __syncthreads();

    int v = cnt[t];
    tmp[t] = v;
    __syncthreads();
    for (int off = 1; off < 1024; off <<= 1) {
        int tv = (t >= off) ? tmp[t - off] : 0;
        __syncthreads();
        tmp[t] += tv;
        __syncthreads();
    }
    int gpos = beg + (tmp[t] - v);          // global CSR start for node0+t
    if (node0 + t <= NN) rowptr[node0 + t] = gpos;
    cur[t] = gpos;
    __syncthreads();

    for (int j = beg + t; j < end; j += 1024) {
        unsigned p = ebuf[j];
        int pos = atomicAdd(&cur[p >> 17], 1);
        col[pos] = (int)(p & 0x1ffffu);
    }
}

// fp32 -> bf16 conversion, 4 elems/thread
__global__ void conv_f2b(const float* __restrict__ src,
                         unsigned short* __restrict__ dst, int n) {
    int i = (blockIdx.x * 256 + threadIdx.x) * 4;
    if (i + 3 < n) {
        float4 v = *(const float4*)(src + i);
        ushort4 o;
        o.x = f2b(v.x); o.y = f2b(v.y); o.z = f2b(v.z); o.w = f2b(v.w);
        *(ushort4*)(dst + i) = o;
    } else {
        for (; i < n; ++i) dst[i] = f2b(src[i]);
    }
}

// all 4 weight matrices (each D*D) in one launch; dsts contiguous
__global__ void conv_w4(const float* __restrict__ s0, const float* __restrict__ s1,
                        const float* __restrict__ s2, const float* __restrict__ s3,
                        unsigned short* __restrict__ dst) {
    int i = (blockIdx.x * 256 + threadIdx.x) * 4;   // [0, 4*D*D)
    const float* srcs[4] = {s0, s1, s2, s3};
    const float* s = srcs[i >> 14];                 // D*D = 16384
    float4 v = *(const float4*)(s + (i & 16383));
    ushort4 o;
    o.x = f2b(v.x); o.y = f2b(v.y); o.z = f2b(v.z); o.w = f2b(v.w);
    *(ushort4*)(dst + i) = o;
}

// mean aggregation over bf16 features; two 32-lane halves per wave, uint2/lane
// (round-8 proven version: 62 us, 3.3 TB/s, FETCH at the coverage floor)
__global__ __launch_bounds__(256) void aggregate(const unsigned short* __restrict__ hb,
                                                 const int* __restrict__ rowptr,
                                                 const int* __restrict__ col,
                                                 unsigned short* __restrict__ aggb) {
    int node = blockIdx.x * 4 + (threadIdx.x >> 6);
    if (node >= NN) return;
    int lane = threadIdx.x & 63;
    int half = lane >> 5;
    int sl   = lane & 31;
    int beg = rowptr[node], end = rowptr[node + 1];
    const uint2* hp = (const uint2*)hb;   // 32 uint2 per row
    float a0 = 0.f, a1 = 0.f, a2 = 0.f, a3 = 0.f;

    int j = beg + half;
    for (; j + 6 < end; j += 8) {
        int c0 = col[j];
        int c1 = col[j + 2];
        int c2 = col[j + 4];
        int c3 = col[j + 6];
        uint2 v0 = hp[c0 * 32 + sl];
        uint2 v1 = hp[c1 * 32 + sl];
        uint2 v2 = hp[c2 * 32 + sl];
        uint2 v3 = hp[c3 * 32 + sl];
        a0 += __uint_as_float(v0.x << 16) + __uint_as_float(v1.x << 16)
            + __uint_as_float(v2.x << 16) + __uint_as_float(v3.x << 16);
        a1 += __uint_as_float(v0.x & 0xffff0000u) + __uint_as_float(v1.x & 0xffff0000u)
            + __uint_as_float(v2.x & 0xffff0000u) + __uint_as_float(v3.x & 0xffff0000u);
        a2 += __uint_as_float(v0.y << 16) + __uint_as_float(v1.y << 16)
            + __uint_as_float(v2.y << 16) + __uint_as_float(v3.y << 16);
        a3 += __uint_as_float(v0.y & 0xffff0000u) + __uint_as_float(v1.y & 0xffff0000u)
            + __uint_as_float(v2.y & 0xffff0000u) + __uint_as_float(v3.y & 0xffff0000u);
    }
    for (; j < end; j += 2) {
        uint2 v = hp[col[j] * 32 + sl];
        a0 += __uint_as_float(v.x << 16);
        a1 += __uint_as_float(v.x & 0xffff0000u);
        a2 += __uint_as_float(v.y << 16);
        a3 += __uint_as_float(v.y & 0xffff0000u);
    }

    a0 += __shfl_xor(a0, 32);
    a1 += __shfl_xor(a1, 32);
    a2 += __shfl_xor(a2, 32);
    a3 += __shfl_xor(a3, 32);

    int deg = end - beg;
    float inv = 1.0f / (float)(deg > 1 ? deg : 1);
    if (half == 0) {
        uint2 o;
        o.x = (unsigned)f2b(a0 * inv) | ((unsigned)f2b(a1 * inv) << 16);
        o.y = (unsigned)f2b(a2 * inv) | ((unsigned)f2b(a3 * inv) << 16);
        ((uint2*)aggb)[(size_t)node * 32 + sl] = o;
    }
}

// out[n][j] = leaky_relu( sum_k agg[n][k]*Wl[j][k] + h[n][k]*Wr[j][k] + b[j], 0.5 )
// MFMA 16x16x32 bf16. Block = 256 thr = 4 waves (2x2), tile 64 rows x 128 cols.
// A/H slabs staged via coalesced uint4 loads into 272B-padded LDS rows.
template <int OUT_F32>
__global__ __launch_bounds__(256) void sage_gemm_mfma(
    const unsigned short* __restrict__ Ab,   // [NN][128] aggregated
    const unsigned short* __restrict__ Hb,   // [NN][128] root
    const unsigned short* __restrict__ Wlb,  // [128][128], row j contiguous in k
    const unsigned short* __restrict__ Wrb,
    const float* __restrict__ bias,
    float* __restrict__ outf,
    unsigned short* __restrict__ outb)
{
    __shared__ unsigned short sA[64][136];   // 17.4 KB (272B rows)
    __shared__ unsigned short sH[64][136];
    const int tid = threadIdx.x;
    const int block0 = blockIdx.x * 64;

    {
        int i = tid;   // 64 rows x 16 quads = 1024; 4 iters of 256 threads
#pragma unroll
        for (int k = 0; k < 4; ++k, i += 256) {
            int row = i >> 4, c16 = i & 15;
            int grow = block0 + row; if (grow >= NN) grow = NN - 1;
            *(uint4*)(&sA[row][c16 * 8]) = *(const uint4*)(Ab + (size_t)grow * D + c16 * 8);
            *(uint4*)(&sH[row][c16 * 8]) = *(const uint4*)(Hb + (size_t)grow * D + c16 * 8);
        }
    }
    __syncthreads();

    const int lane = tid & 63;
    const int wid  = tid >> 6;
    const int r  = lane & 15;
    const int kg = lane >> 4;
    const int rbase = (wid >> 1) * 32;     // 0 or 32
    const int col0  = (wid & 1) * 64;

    float bv[4];
#pragma unroll
    for (int c = 0; c < 4; ++c) bv[c] = bias[col0 + c * 16 + r];

    f32x4 acc[2][4];
#pragma unroll
    for (int m = 0; m < 2; ++m)
#pragma unroll
        for (int c = 0; c < 4; ++c) acc[m][c] = (f32x4){0.f, 0.f, 0.f, 0.f};

#pragma unroll
    for (int ks = 0; ks < 8; ++ks) {
        const unsigned short (*S)[136] = (ks < 4) ? sA : sH;
        const unsigned short* W = (ks < 4) ? Wlb : Wrb;
        const int kk = (ks & 3) * 32 + kg * 8;
        bf16x8 a0 = *(const bf16x8*)(&S[rbase + r][kk]);
        bf16x8 a1 = *(const bf16x8*)(&S[rbase + 16 + r][kk]);
        bf16x8 bw[4];
#pragma unroll
        for (int c = 0; c < 4; ++c)
            bw[c] = *(const bf16x8*)(W + (size_t)(col0 + c * 16 + r) * D + kk);
#pragma unroll
        for (int c = 0; c < 4; ++c) {
            acc[0][c] = __builtin_amdgcn_mfma_f32_16x16x32_bf16(a0, bw[c], acc[0][c], 0, 0, 0);
            acc[1][c] = __builtin_amdgcn_mfma_f32_16x16x32_bf16(a1, bw[c], acc[1][c], 0, 0, 0);
        }
    }

    // C/D layout: col = c*16 + (lane&15), row = m*16 + (lane>>4)*4 + q   [m89]
#pragma unroll
    for (int m = 0; m < 2; ++m) {
#pragma unroll
        for (int q = 0; q < 4; ++q) {
            int row = block0 + rbase + m * 16 + kg * 4 + q;
            if (row < NN) {
#pragma unroll
                for (int c = 0; c < 4; ++c) {
                    float v = acc[m][c][q] + bv[c];
                    v = v > 0.f ? v : 0.5f * v;
                    int colj = col0 + c * 16 + r;
                    if (OUT_F32) outf[(size_t)row * D + colj] = v;
                    else         outb[(size_t)row * D + colj] = f2b(v);
                }
            }
        }
    }
}

extern "C" void kernel_launch(void* const* d_in, const int* in_sizes, int n_in,
                              void* d_out, int out_size, void* d_ws, size_t ws_size,
                              hipStream_t stream) {
    const float* x   = (const float*)d_in[0];
    const int*   ei  = (const int*)d_in[1];
    const float* W1l = (const float*)d_in[2];
    const float* W1r = (const float*)d_in[3];
    const float* b1  = (const float*)d_in[4];
    const float* W2l = (const float*)d_in[5];
    const float* W2r = (const float*)d_in[6];
    const float* b2  = (const float*)d_in[7];
    float* out = (float*)d_out;

    char* ws = (char*)d_ws;
    size_t off = 0;
    auto alloc = [&](size_t bytes) {
        void* p = ws + off;
        off = (off + bytes + 255) & ~(size_t)255;
        return p;
    };
    int* rowptr = (int*)alloc((NN + 2) * 4);
    int* bcnt   = (int*)alloc((NB + 1) * 4);
    int* bbase  = (int*)alloc((NB + 1) * 4);
    int* gcur   = (int*)alloc((NB + 1) * 4);
    int* col    = (int*)alloc((size_t)NE * 4);
    unsigned short* xb   = (unsigned short*)alloc((size_t)NN * D * 2);
    unsigned short* aggb = (unsigned short*)alloc((size_t)NN * D * 2);
    unsigned short* h1b  = (unsigned short*)alloc((size_t)NN * D * 2);
    unsigned short* wb   = (unsigned short*)alloc((size_t)4 * D * D * 2);
    unsigned short* w1lb = wb;
    unsigned short* w1rb = wb + D * D;
    unsigned short* w2lb = wb + 2 * D * D;
    unsigned short* w2rb = wb + 3 * D * D;
    // ebuf (6.4 MB) aliases h1b (25.6 MB): ebuf dead before h1b is written
    unsigned* ebuf = (unsigned*)h1b;

    // ---- CSR build: bin to buckets, then one block per bucket sorts locally ----
    hipMemsetAsync(bcnt, 0, (NB + 1) * 4, stream);
    bucket_count<<<(NE + BCHUNK - 1) / BCHUNK, 256, 0, stream>>>(ei, bcnt);
    scan98<<<1, 128, 0, stream>>>(bcnt, bbase, gcur);
    bin_scatter<<<(NE + BCHUNK - 1) / BCHUNK, 256, 0, stream>>>(ei, gcur, ebuf);
    sort_bucket<<<NB, 1024, 0, stream>>>(ebuf, bbase, rowptr, col);

    // ---- bf16 conversions ----
    conv_f2b<<<(NN * D / 4 + 255) / 256, 256, 0, stream>>>(x, xb, NN * D);
    conv_w4<<<(4 * D * D / 4 + 255) / 256, 256, 0, stream>>>(W1l, W1r, W2l, W2r, wb);

    // ---- layer 1 ----
    aggregate<<<(NN + 3) / 4, 256, 0, stream>>>(xb, rowptr, col, aggb);
    sage_gemm_mfma<0><<<(NN + 63) / 64, 256, 0, stream>>>(aggb, xb, w1lb, w1rb, b1,
                                                          nullptr, h1b);
    // ---- layer 2 ----
    aggregate<<<(NN + 3) / 4, 256, 0, stream>>>(h1b, rowptr, col, aggb);
    sage_gemm_mfma<1><<<(NN + 63) / 64, 256, 0, stream>>>(aggb, h1b, w2lb, w2rb, b2,
                                                          out, nullptr);
}